// Round 3
// baseline (16300.475 us; speedup 1.0000x reference)
//
#include <hip/hip_runtime.h>

typedef _Float16 h16;
typedef __attribute__((ext_vector_type(2))) _Float16 h16x2;
typedef __attribute__((ext_vector_type(4))) _Float16 h16x4;
typedef __attribute__((ext_vector_type(8))) _Float16 h16x8;
typedef __attribute__((ext_vector_type(4))) float    f32x4;
typedef unsigned long long u64;

constexpr int B_  = 16;
constexpr int T_  = 2048;
constexpr int D_  = 512;
constexpr int H_  = 512;
constexpr int O_  = 256;
constexpr int G4_ = 2048;           // 4*H
constexpr int BT_ = B_ * T_;
constexpr int DR_ = 32;             // ring depth (slots)

__device__ __forceinline__ float sigm(float x)   { return 1.f / (1.f + __expf(-x)); }
__device__ __forceinline__ float tanh_f(float x) { return 1.f - 2.f / (1.f + __expf(2.f * x)); }

// ---------------- prep: fp32 x -> fp16 X, and mask bits ----------------
__global__ void k_prep_x(const float* __restrict__ x, h16* __restrict__ Xh,
                         unsigned* __restrict__ maskbits) {
  const int row = blockIdx.x;              // b*T + t
  const int b = row >> 11, t = row & 2047;
  const float2* xr = (const float2*)(x + (size_t)row * D_);
  float2 v = xr[threadIdx.x];
  h16x2 hv = { (h16)v.x, (h16)v.y };
  *(h16x2*)(Xh + (size_t)row * D_ + threadIdx.x * 2) = hv;
  float s = v.x + v.y;
  #pragma unroll
  for (int off = 32; off > 0; off >>= 1) s += __shfl_down(s, off, 64);
  __shared__ float red[4];
  const int lane = threadIdx.x & 63, wv = threadIdx.x >> 6;
  if (lane == 0) red[wv] = s;
  __syncthreads();
  if (threadIdx.x == 0) {
    float tot = red[0] + red[1] + red[2] + red[3];
    if (tot != 0.f) atomicOr(&maskbits[t], 1u << b);
  }
}

// ---------------- fp32 -> fp16 convert (weights) ----------------
__global__ void k_cvt(const float* __restrict__ s, h16* __restrict__ d, int n4) {
  int i = blockIdx.x * 256 + threadIdx.x;
  if (i < n4) {
    f32x4 v = ((const f32x4*)s)[i];
    h16x4 o = { (h16)v.x, (h16)v.y, (h16)v.z, (h16)v.w };
    ((h16x4*)d)[i] = o;
  }
}

__global__ void k_bias(const float* __restrict__ a, const float* __restrict__ b,
                       float* __restrict__ o, int n) {
  int i = blockIdx.x * 256 + threadIdx.x;
  if (i < n) o[i] = a[i] + b[i];
}

// ---------------- GEMM: C[m][n] = sum_k A[m,k]*B[n,k] ----------------
__global__ __launch_bounds__(256, 2)
void k_gemm(const h16* __restrict__ A, const h16* __restrict__ Bm, h16* __restrict__ C,
            int M, int N, int K) {
  __shared__ h16 As[128 * 32];
  __shared__ h16 Bs[128 * 32];
  const int tiles_n = N >> 7;
  const int tm = blockIdx.x / tiles_n, tn = blockIdx.x % tiles_n;
  const int tid = threadIdx.x, lane = tid & 63, wv = tid >> 6;
  const int wm = (wv >> 1) * 64, wn = (wv & 1) * 64;
  const int ml = lane & 15, qd = lane >> 4;
  f32x4 acc[4][4] = {};
  const h16* Arow = A + (size_t)(tm * 128) * K;
  const h16* Brow = Bm + (size_t)(tn * 128) * K;
  for (int kt = 0; kt < K; kt += 32) {
    __syncthreads();
    #pragma unroll
    for (int p = 0; p < 2; ++p) {
      int ch = tid + p * 256;
      int r = ch >> 2, qq = ch & 3;
      int sidx = r * 4 + ((qq + r) & 3);
      *(h16x8*)(As + sidx * 8) = *(const h16x8*)(Arow + (size_t)r * K + kt + qq * 8);
      *(h16x8*)(Bs + sidx * 8) = *(const h16x8*)(Brow + (size_t)r * K + kt + qq * 8);
    }
    __syncthreads();
    h16x8 af[4], bfv[4];
    #pragma unroll
    for (int i = 0; i < 4; ++i) {
      int ra = wm + i * 16 + ml;
      af[i]  = *(const h16x8*)(As + (ra * 4 + ((qd + ra) & 3)) * 8);
      int rb = wn + i * 16 + ml;
      bfv[i] = *(const h16x8*)(Bs + (rb * 4 + ((qd + rb) & 3)) * 8);
    }
    #pragma unroll
    for (int i = 0; i < 4; ++i)
      #pragma unroll
      for (int j = 0; j < 4; ++j)
        acc[i][j] = __builtin_amdgcn_mfma_f32_16x16x32_f16(af[i], bfv[j], acc[i][j], 0, 0, 0);
  }
  const int colb = lane & 15, rowq = (lane >> 4) * 4;
  #pragma unroll
  for (int i = 0; i < 4; ++i)
    #pragma unroll
    for (int j = 0; j < 4; ++j) {
      int row0 = tm * 128 + wm + i * 16 + rowq;
      int col  = tn * 128 + wn + j * 16 + colb;
      #pragma unroll
      for (int r = 0; r < 4; ++r)
        C[(size_t)(row0 + r) * N + col] = (h16)acc[i][j][r];
    }
}

// ---------------- fused 2-layer persistent recurrence, flag+data protocol ----
// 64 WGs: wg<32 => layer0 slice g=wg ; wg>=32 => layer1 slice g=wg-32.
// Data rings H0d/H1d: tagless h16, DR_ slots of [16 samples][512]. Slot s holds
// h(s mod DR_) where flag value >= s proves validity.
// Flags Fl0/Fl1: per-WG monotone u32 = last published step (release-store after
// a tail __syncthreads; consumers spin on the 2 producers covering their chunk).
__global__ __launch_bounds__(256, 1)
void k_lstm2(const h16* __restrict__ G,
             const h16* __restrict__ Whh0,
             const h16* __restrict__ Wih1,
             const h16* __restrict__ Whh1,
             const float* __restrict__ bias0,
             const float* __restrict__ bias1,
             const unsigned* __restrict__ maskbits,
             h16* H0d, h16* H1d, unsigned* Fl0, unsigned* Fl1, float* hT_out) {
  const int wg = blockIdx.x;
  const bool l1 = wg >= 32;
  const int g = l1 ? (wg - 32) : wg;
  const int tid = threadIdx.x, lane = tid & 63, w = tid >> 6;
  const int nl = lane & 15, qd = lane >> 4;
  const int sample = tid >> 4, c = tid & 15;     // 32-col chunk id

  __shared__ h16 Hst0[16 * 520];
  __shared__ h16 Hst1[16 * 520];
  __shared__ float gate_ex[4][16][17];
  __shared__ float c_st[16][16];
  __shared__ unsigned mword;

  h16x8 a_hh[16], a_ih[16];
  {
    const h16* Whh = l1 ? Whh1 : Whh0;
    const h16* wr = Whh + (size_t)(w * 512 + g * 16 + nl) * 512 + qd * 8;
    #pragma unroll
    for (int kt = 0; kt < 16; ++kt) a_hh[kt] = *(const h16x8*)(wr + kt * 32);
  }
  if (l1) {
    const h16* wr = Wih1 + (size_t)(w * 512 + g * 16 + nl) * 512 + qd * 8;
    #pragma unroll
    for (int kt = 0; kt < 16; ++kt) a_ih[kt] = *(const h16x8*)(wr + kt * 32);
  }
  const float* bias = l1 ? bias1 : bias0;
  float bias_v[4];
  #pragma unroll
  for (int r = 0; r < 4; ++r) bias_v[r] = bias[w * 512 + g * 16 + qd * 4 + r];

  c_st[tid >> 4][tid & 15] = 0.f;
  for (int i = tid; i < 16 * 520; i += 256) { Hst0[i] = (h16)0.f; Hst1[i] = (h16)0.f; }
  __syncthreads();

  h16* myring = l1 ? H1d : H0d;
  unsigned* myflag = l1 ? Fl1 : Fl0;

  // register-prefetched x-gates (layer0 only)
  h16x4 gv_cur = {}, gv_next = {};
  if (!l1)
    gv_cur = *(const h16x4*)(G + ((size_t)nl * T_ + 0) * G4_ + w * 512 + g * 16 + qd * 4);

  for (int t = 0; t < T_; ++t) {
    if (!l1) {
      // amortized back-pressure: every 16 steps ensure L1 within 8 steps
      if ((t & 15) == 0 && t >= 16 && tid < 32) {
        const unsigned bt = (unsigned)(t - 8);
        while (__hip_atomic_load(&Fl1[tid], __ATOMIC_RELAXED, __HIP_MEMORY_SCOPE_AGENT) < bt)
          __builtin_amdgcn_s_sleep(2);
      }
      if (t > 0) {
        const u64* fp = (const u64*)(Fl0 + (c << 1));
        const unsigned tgt = (unsigned)t;
        for (;;) {
          u64 v = __hip_atomic_load(fp, __ATOMIC_ACQUIRE, __HIP_MEMORY_SCOPE_AGENT);
          if ((unsigned)v >= tgt && (unsigned)(v >> 32) >= tgt) break;
        }
        const u64* dp = (const u64*)(H0d + ((size_t)((t & (DR_ - 1)) * 16 + sample)) * 512 + c * 32);
        u64 d[8];
        #pragma unroll
        for (int i = 0; i < 8; ++i)
          d[i] = __hip_atomic_load(dp + i, __ATOMIC_RELAXED, __HIP_MEMORY_SCOPE_AGENT);
        u64* dst = (u64*)(Hst0 + sample * 520 + c * 32);
        #pragma unroll
        for (int i = 0; i < 8; ++i) dst[i] = d[i];
      }
      // prefetch next step's x-gates (independent of the spin above)
      {
        int tn = (t + 1 < T_) ? (t + 1) : t;
        gv_next = *(const h16x4*)(G + ((size_t)nl * T_ + tn) * G4_ + w * 512 + g * 16 + qd * 4);
      }
      if (tid == 0) mword = maskbits[t];
      __syncthreads();
      f32x4 acc = {0.f, 0.f, 0.f, 0.f};
      if (t > 0) {
        #pragma unroll
        for (int kt = 0; kt < 16; ++kt) {
          h16x8 bfr = *(const h16x8*)(Hst0 + nl * 520 + kt * 32 + qd * 8);
          acc = __builtin_amdgcn_mfma_f32_16x16x32_f16(a_hh[kt], bfr, acc, 0, 0, 0);
        }
      }
      #pragma unroll
      for (int r = 0; r < 4; ++r) {
        float pre = acc[r] + bias_v[r] + (float)gv_cur[r];
        gate_ex[w][qd * 4 + r][nl] = (w == 2) ? tanh_f(pre) : sigm(pre);
      }
      gv_cur = gv_next;
    } else {
      // L1: single merged spin on own pair (>= t) and L0 pair (>= t+1)
      const u64* fp0 = (const u64*)(Fl0 + (c << 1));
      const u64* fp1 = (const u64*)(Fl1 + (c << 1));
      const unsigned tgt0 = (unsigned)(t + 1), tgt1 = (unsigned)t;
      for (;;) {
        u64 v0 = __hip_atomic_load(fp0, __ATOMIC_ACQUIRE, __HIP_MEMORY_SCOPE_AGENT);
        bool ok = ((unsigned)v0 >= tgt0) && ((unsigned)(v0 >> 32) >= tgt0);
        if (t > 0) {
          u64 v1 = __hip_atomic_load(fp1, __ATOMIC_ACQUIRE, __HIP_MEMORY_SCOPE_AGENT);
          ok &= ((unsigned)v1 >= tgt1) && ((unsigned)(v1 >> 32) >= tgt1);
        }
        if (ok) break;
      }
      {
        const u64* dp0 = (const u64*)(H0d + ((size_t)(((t + 1) & (DR_ - 1)) * 16 + sample)) * 512 + c * 32);
        u64 d0[8];
        #pragma unroll
        for (int i = 0; i < 8; ++i)
          d0[i] = __hip_atomic_load(dp0 + i, __ATOMIC_RELAXED, __HIP_MEMORY_SCOPE_AGENT);
        u64* dst0 = (u64*)(Hst0 + sample * 520 + c * 32);
        #pragma unroll
        for (int i = 0; i < 8; ++i) dst0[i] = d0[i];
        if (t > 0) {
          const u64* dp1 = (const u64*)(H1d + ((size_t)((t & (DR_ - 1)) * 16 + sample)) * 512 + c * 32);
          u64 d1[8];
          #pragma unroll
          for (int i = 0; i < 8; ++i)
            d1[i] = __hip_atomic_load(dp1 + i, __ATOMIC_RELAXED, __HIP_MEMORY_SCOPE_AGENT);
          u64* dst1 = (u64*)(Hst1 + sample * 520 + c * 32);
          #pragma unroll
          for (int i = 0; i < 8; ++i) dst1[i] = d1[i];
        }
      }
      if (tid == 0) mword = maskbits[t];
      __syncthreads();
      f32x4 acc = {0.f, 0.f, 0.f, 0.f};
      if (t > 0) {
        #pragma unroll
        for (int kt = 0; kt < 16; ++kt) {
          h16x8 bfr = *(const h16x8*)(Hst1 + nl * 520 + kt * 32 + qd * 8);
          acc = __builtin_amdgcn_mfma_f32_16x16x32_f16(a_hh[kt], bfr, acc, 0, 0, 0);
        }
      }
      #pragma unroll
      for (int kt = 0; kt < 16; ++kt) {
        h16x8 bfr = *(const h16x8*)(Hst0 + nl * 520 + kt * 32 + qd * 8);
        acc = __builtin_amdgcn_mfma_f32_16x16x32_f16(a_ih[kt], bfr, acc, 0, 0, 0);
      }
      #pragma unroll
      for (int r = 0; r < 4; ++r) {
        float pre = acc[r] + bias_v[r];
        gate_ex[w][qd * 4 + r][nl] = (w == 2) ? tanh_f(pre) : sigm(pre);
      }
    }
    __syncthreads();

    // cell update: 128 threads, 2 adjacent j each -> one packed u32 ring store
    if (tid < 128) {
      const int n = tid >> 3, j = (tid & 7) * 2;
      const h16* Hprev = l1 ? Hst1 : Hst0;
      const bool msk = (mword >> n) & 1u;
      float hnf[2];
      #pragma unroll
      for (int u = 0; u < 2; ++u) {
        const int jj = j + u;
        float iv = gate_ex[0][jj][n], fv = gate_ex[1][jj][n];
        float gg = gate_ex[2][jj][n], ov = gate_ex[3][jj][n];
        float c_old = c_st[jj][n];
        float c_new = msk ? (fv * c_old + iv * gg) : c_old;
        float h_old = (float)Hprev[n * 520 + g * 16 + jj];
        hnf[u] = msk ? (ov * tanh_f(c_new)) : h_old;
        c_st[jj][n] = c_new;
      }
      h16 h0v = (h16)hnf[0], h1v = (h16)hnf[1];
      unsigned short b0, b1;
      __builtin_memcpy(&b0, &h0v, 2); __builtin_memcpy(&b1, &h1v, 2);
      unsigned pv = (unsigned)b0 | ((unsigned)b1 << 16);
      unsigned* wp = (unsigned*)(myring + ((size_t)((((t + 1) & (DR_ - 1)) * 16) + n)) * 512 + g * 16 + j);
      __hip_atomic_store(wp, pv, __ATOMIC_RELAXED, __HIP_MEMORY_SCOPE_AGENT);
      if (l1 && t == T_ - 1) {
        hT_out[n * H_ + g * 16 + j]     = hnf[0];
        hT_out[n * H_ + g * 16 + j + 1] = hnf[1];
      }
    }
    __syncthreads();   // all ring stores done; LDS safe for next step
    if (tid == 0)
      __hip_atomic_store(&myflag[g], (unsigned)(t + 1), __ATOMIC_RELEASE, __HIP_MEMORY_SCOPE_AGENT);
  }
}

// ---------------- final FC ----------------
__global__ void k_fc(const float* __restrict__ hT, const float* __restrict__ Wfc,
                     const float* __restrict__ bfc, float* __restrict__ out) {
  const int b = blockIdx.x;
  __shared__ float hs[H_];
  for (int i = threadIdx.x; i < H_; i += 256) hs[i] = hT[(size_t)b * H_ + i];
  __syncthreads();
  const int o = threadIdx.x;
  const float* wr = Wfc + (size_t)o * H_;
  float s = bfc[o];
  for (int k = 0; k < H_; k += 4) {
    f32x4 w4 = *(const f32x4*)(wr + k);
    s += hs[k] * w4.x + hs[k + 1] * w4.y + hs[k + 2] * w4.z + hs[k + 3] * w4.w;
  }
  out[(size_t)b * O_ + o] = s;
}

extern "C" void kernel_launch(void* const* d_in, const int* in_sizes, int n_in,
                              void* d_out, int out_size, void* d_ws, size_t ws_size,
                              hipStream_t stream) {
  const float* x    = (const float*)d_in[0];
  const float* Wih0 = (const float*)d_in[1];
  const float* Whh0 = (const float*)d_in[2];
  const float* bih0 = (const float*)d_in[3];
  const float* bhh0 = (const float*)d_in[4];
  const float* Wih1 = (const float*)d_in[5];
  const float* Whh1 = (const float*)d_in[6];
  const float* bih1 = (const float*)d_in[7];
  const float* bhh1 = (const float*)d_in[8];
  const float* Wfc  = (const float*)d_in[9];
  const float* bfc  = (const float*)d_in[10];

  char* base = (char*)d_ws;
  size_t off = 0;
  auto alloc = [&](size_t bytes) -> void* {
    void* r = base + off;
    off = (off + bytes + 255) & ~(size_t)255;
    return r;
  };
  h16* Xh   = (h16*)alloc((size_t)BT_ * D_ * 2);
  h16* Gbuf = (h16*)alloc((size_t)BT_ * G4_ * 2);
  h16* Wb0  = (h16*)alloc((size_t)G4_ * D_ * 2);
  h16* Wb1  = (h16*)alloc((size_t)G4_ * H_ * 2);   // Whh0
  h16* Wb2  = (h16*)alloc((size_t)G4_ * H_ * 2);   // Wih1
  h16* Wb3  = (h16*)alloc((size_t)G4_ * H_ * 2);   // Whh1
  float* bs0 = (float*)alloc(G4_ * 4);
  float* bs1 = (float*)alloc(G4_ * 4);
  unsigned* maskbits = (unsigned*)alloc(T_ * 4);
  h16* H0d = (h16*)alloc((size_t)DR_ * 16 * 512 * 2);
  h16* H1d = (h16*)alloc((size_t)DR_ * 16 * 512 * 2);
  unsigned* Fl0 = (unsigned*)alloc(4096);
  unsigned* Fl1 = (unsigned*)alloc(4096);
  float* hT = (float*)alloc((size_t)B_ * H_ * 4);

  hipMemsetAsync(maskbits, 0, T_ * 4, stream);
  hipMemsetAsync(Fl0, 0, 4096, stream);
  hipMemsetAsync(Fl1, 0, 4096, stream);
  k_prep_x<<<BT_, 256, 0, stream>>>(x, Xh, maskbits);
  const int wn4 = G4_ * D_ / 4;
  k_cvt<<<(wn4 + 255) / 256, 256, 0, stream>>>(Wih0, Wb0, wn4);
  k_cvt<<<(wn4 + 255) / 256, 256, 0, stream>>>(Whh0, Wb1, wn4);
  k_cvt<<<(wn4 + 255) / 256, 256, 0, stream>>>(Wih1, Wb2, wn4);
  k_cvt<<<(wn4 + 255) / 256, 256, 0, stream>>>(Whh1, Wb3, wn4);
  k_bias<<<(G4_ + 255) / 256, 256, 0, stream>>>(bih0, bhh0, bs0, G4_);
  k_bias<<<(G4_ + 255) / 256, 256, 0, stream>>>(bih1, bhh1, bs1, G4_);

  k_gemm<<<(BT_ / 128) * (G4_ / 128), 256, 0, stream>>>(Xh, Wb0, Gbuf, BT_, G4_, D_);
  k_lstm2<<<64, 256, 0, stream>>>(Gbuf, Wb1, Wb2, Wb3, bs0, bs1, maskbits,
                                  H0d, H1d, Fl0, Fl1, hT);
  k_fc<<<B_, 256, 0, stream>>>(hT, Wfc, bfc, (float*)d_out);
}